// Round 1
// baseline (362.379 us; speedup 1.0000x reference)
//
#include <hip/hip_runtime.h>
#include <hip/hip_bf16.h>
#include <cstdint>
#include <cstddef>

#define TT 2048
#define DDIM 2048
#define NH 32
#define NKV 8
#define HDIM 64

typedef __attribute__((ext_vector_type(8))) short bf16x8;
typedef __attribute__((ext_vector_type(4))) float f32x4;

__device__ __forceinline__ unsigned short f2bf(float f) {
  unsigned u = __float_as_uint(f);
  unsigned r = 0x7FFFu + ((u >> 16) & 1u);
  return (unsigned short)((u + r) >> 16);
}

__device__ __forceinline__ void gl_lds16(const void* g, void* l) {
  __builtin_amdgcn_global_load_lds(
      (const __attribute__((address_space(1))) void*)g,
      (__attribute__((address_space(3))) void*)l, 16, 0, 0);
}

// ---------------- cast f32 -> bf16 (4-wide) ----------------
__global__ __launch_bounds__(256)
void cast_bf16_kernel(const float* __restrict__ src, unsigned short* __restrict__ dst, int n4) {
  int i = blockIdx.x * 256 + threadIdx.x;
  if (i >= n4) return;
  float4 f = reinterpret_cast<const float4*>(src)[i];
  ushort4 o;
  o.x = f2bf(f.x); o.y = f2bf(f.y); o.z = f2bf(f.z); o.w = f2bf(f.w);
  reinterpret_cast<ushort4*>(dst)[i] = o;
}

// ---------------- GEMM: C[m][n] = sum_k A[m][k] * B[n][k] ----------------
// A: M x K bf16 row-major; B: N x K bf16 row-major; C: M x N f32 row-major.
// 128x128 tile, BK=32, 256 threads (4 waves, 2x2), global_load_lds staging.
__global__ __launch_bounds__(256)
void gemm_bt_kernel(const unsigned short* __restrict__ A,
                    const unsigned short* __restrict__ B,
                    float* __restrict__ C, int M, int N, int K) {
  __shared__ __align__(16) unsigned short As[128 * 32];
  __shared__ __align__(16) unsigned short Bs[128 * 32];
  const int bm = blockIdx.x, bn = blockIdx.y;
  const int tid = threadIdx.x;
  const int wave = tid >> 6, lane = tid & 63;
  const int wm = wave >> 1, wn = wave & 1;
  const int lr = lane & 15, lk = (lane >> 4) * 8;
  const int ldr = lane >> 2;          // 0..15 row within 16-row issue block
  const int ldc = (lane & 3) * 8;     // 0,8,16,24 element col

  f32x4 acc[4][4];
  for (int i = 0; i < 4; ++i)
    for (int j = 0; j < 4; ++j)
      acc[i][j] = (f32x4){0.f, 0.f, 0.f, 0.f};

  const size_t arow = (size_t)(bm * 128) * K;
  const size_t brow = (size_t)(bn * 128) * K;

  for (int k0 = 0; k0 < K; k0 += 32) {
    __syncthreads();  // previous compute done reading LDS
    for (int i = 0; i < 2; ++i) {
      int rblk = wave * 2 + i;        // 0..7, 16 rows each
      int r = rblk * 16 + ldr;
      gl_lds16(A + arow + (size_t)r * K + k0 + ldc, &As[rblk * 16 * 32]);
      gl_lds16(B + brow + (size_t)r * K + k0 + ldc, &Bs[rblk * 16 * 32]);
    }
    __syncthreads();  // implicit vmcnt(0) drain -> staged data visible

    bf16x8 af[4], bfr[4];
    for (int mi = 0; mi < 4; ++mi)
      af[mi] = *reinterpret_cast<const bf16x8*>(&As[(wm * 64 + mi * 16 + lr) * 32 + lk]);
    for (int ni = 0; ni < 4; ++ni)
      bfr[ni] = *reinterpret_cast<const bf16x8*>(&Bs[(wn * 64 + ni * 16 + lr) * 32 + lk]);
    for (int mi = 0; mi < 4; ++mi)
      for (int ni = 0; ni < 4; ++ni)
        acc[mi][ni] = __builtin_amdgcn_mfma_f32_16x16x32_bf16(af[mi], bfr[ni], acc[mi][ni], 0, 0, 0);
  }

  // epilogue: C/D layout col = lane&15, row = (lane>>4)*4 + reg
  for (int mi = 0; mi < 4; ++mi)
    for (int ni = 0; ni < 4; ++ni) {
      int col = bn * 128 + wn * 64 + ni * 16 + lr;
      int rbase = bm * 128 + wm * 64 + mi * 16 + (lane >> 4) * 4;
      for (int r = 0; r < 4; ++r)
        C[(size_t)(rbase + r) * N + col] = acc[mi][ni][r];
    }
}

// ---------------- RoPE + transpose to head-major bf16 ----------------
// src: [T][nheads*64] f32 ; dst: [nheads][T][64] bf16
__global__ __launch_bounds__(256)
void rope_transpose_kernel(const float* __restrict__ src, unsigned short* __restrict__ dst,
                           int nheads) {
  int idx = blockIdx.x * 256 + threadIdx.x;
  int ppt = nheads * 32;  // pairs per t
  if (idx >= TT * ppt) return;
  int t = idx / ppt;
  int p = idx - t * ppt;
  int h = p >> 5;
  int i = p & 31;
  float2 q = reinterpret_cast<const float2*>(src)[(size_t)t * ppt + p];
  // theta = 10000^(-2i/64) = 2^(-(2i/64)*log2(10000))
  float theta = exp2f(-(float)(2 * i) * (13.287712379549449f / 64.0f));
  float freq = (float)t * theta;
  float s, c;
  __sincosf(freq, &s, &c);
  float r1 = q.x * c - q.y * s;
  float r2 = q.x * s + q.y * c;
  size_t o = ((size_t)h * TT + t) * HDIM + 2 * i;
  ushort2 ov; ov.x = f2bf(r1); ov.y = f2bf(r2);
  *reinterpret_cast<ushort2*>(&dst[o]) = ov;
}

// ---------------- V transpose: [T][512] f32 -> [8][64][T] bf16 ----------------
__global__ __launch_bounds__(256)
void transpose_v_kernel(const float* __restrict__ src, unsigned short* __restrict__ dst) {
  int idx = blockIdx.x * 256 + threadIdx.x;  // over 512*2048
  if (idx >= 512 * TT) return;
  int t = idx & (TT - 1);
  int c = idx >> 11;  // 0..511 = hkv*64 + d
  dst[idx] = f2bf(src[(size_t)t * 512 + c]);
}

// ---------------- flash attention (GQA, causal) ----------------
// qh: [32][T][64] bf16 ; kh: [8][T][64] bf16 ; vt: [8][64][T] bf16
// y:  [T][2048] bf16
__global__ __launch_bounds__(256)
void attn_kernel(const unsigned short* __restrict__ qh,
                 const unsigned short* __restrict__ kh,
                 const unsigned short* __restrict__ vt,
                 unsigned short* __restrict__ y) {
  __shared__ __align__(16) unsigned short Ks[64 * 64];    // [j][d]
  __shared__ __align__(16) unsigned short Vts[64 * 64];   // [d][j]
  __shared__ __align__(16) unsigned short Ps[4][16 * 64]; // per-wave P [row][j]
  const int qb = blockIdx.x, h = blockIdx.y, hkv = h >> 2;
  const int tid = threadIdx.x, wave = tid >> 6, lane = tid & 63;
  const int lr = lane & 15, lk = (lane >> 4) * 8;
  const int ldr8 = lane >> 3;          // 0..7
  const int ldc8 = (lane & 7) * 8;     // element col (16B units)

  // Q fragments held in registers for the whole KV loop
  bf16x8 qa[2];
  {
    const unsigned short* qbase = qh + ((size_t)h * TT + qb * 64 + wave * 16 + lr) * HDIM;
    qa[0] = *reinterpret_cast<const bf16x8*>(qbase + lk);
    qa[1] = *reinterpret_cast<const bf16x8*>(qbase + 32 + lk);
  }

  f32x4 acc_o[4];
  for (int i = 0; i < 4; ++i) acc_o[i] = (f32x4){0.f, 0.f, 0.f, 0.f};
  float m_r[4], l_r[4];
  for (int r = 0; r < 4; ++r) { m_r[r] = -1e30f; l_r[r] = 0.f; }
  const int gq = qb * 64 + wave * 16 + (lane >> 4) * 4;  // + reg -> global q row

  for (int jb = 0; jb <= qb; ++jb) {
    __syncthreads();  // everyone done with previous K/V tiles
    for (int i = 0; i < 2; ++i) {
      int rblk = wave * 2 + i;  // 0..7, 8 rows each
      int r = rblk * 8 + ldr8;
      gl_lds16(kh + ((size_t)hkv * TT + jb * 64 + r) * HDIM + ldc8, &Ks[rblk * 8 * 64]);
      gl_lds16(vt + ((size_t)hkv * HDIM + r) * TT + jb * 64 + ldc8, &Vts[rblk * 8 * 64]);
    }
    __syncthreads();  // staged

    // S = Q K^T  (rows: q, cols: j)
    f32x4 s[4];
    for (int ni = 0; ni < 4; ++ni) s[ni] = (f32x4){0.f, 0.f, 0.f, 0.f};
    for (int ni = 0; ni < 4; ++ni) {
      bf16x8 kb0 = *reinterpret_cast<const bf16x8*>(&Ks[(ni * 16 + lr) * 64 + lk]);
      bf16x8 kb1 = *reinterpret_cast<const bf16x8*>(&Ks[(ni * 16 + lr) * 64 + 32 + lk]);
      s[ni] = __builtin_amdgcn_mfma_f32_16x16x32_bf16(qa[0], kb0, s[ni], 0, 0, 0);
      s[ni] = __builtin_amdgcn_mfma_f32_16x16x32_bf16(qa[1], kb1, s[ni], 0, 0, 0);
    }
    // scale + causal mask
    for (int ni = 0; ni < 4; ++ni) {
      int jg = jb * 64 + ni * 16 + lr;
      for (int r = 0; r < 4; ++r) {
        float v = s[ni][r] * 0.125f;
        s[ni][r] = (jg <= gq + r) ? v : -1e30f;
      }
    }
    // online softmax (rows live across 16-lane groups; reg r = row offset)
    float alpha[4];
    for (int r = 0; r < 4; ++r) {
      float mx = fmaxf(fmaxf(s[0][r], s[1][r]), fmaxf(s[2][r], s[3][r]));
      for (int off = 1; off < 16; off <<= 1) mx = fmaxf(mx, __shfl_xor(mx, off));
      float mn = fmaxf(m_r[r], mx);
      alpha[r] = __expf(m_r[r] - mn);
      m_r[r] = mn;
    }
    float rs[4] = {0.f, 0.f, 0.f, 0.f};
    for (int ni = 0; ni < 4; ++ni)
      for (int r = 0; r < 4; ++r) {
        float p = __expf(s[ni][r] - m_r[r]);
        s[ni][r] = p;
        rs[r] += p;
      }
    for (int r = 0; r < 4; ++r) {
      for (int off = 1; off < 16; off <<= 1) rs[r] += __shfl_xor(rs[r], off);
      l_r[r] = l_r[r] * alpha[r] + rs[r];
    }
    for (int db = 0; db < 4; ++db)
      for (int r = 0; r < 4; ++r) acc_o[db][r] *= alpha[r];

    // P -> LDS (bf16) to re-enter MFMA A-layout
    for (int ni = 0; ni < 4; ++ni)
      for (int r = 0; r < 4; ++r)
        Ps[wave][((lane >> 4) * 4 + r) * 64 + ni * 16 + lr] = f2bf(s[ni][r]);
    asm volatile("s_waitcnt lgkmcnt(0)" ::: "memory");
    __builtin_amdgcn_sched_barrier(0);

    // O += P V
    for (int kc = 0; kc < 2; ++kc) {
      bf16x8 pa = *reinterpret_cast<const bf16x8*>(&Ps[wave][lr * 64 + kc * 32 + lk]);
      for (int db = 0; db < 4; ++db) {
        bf16x8 vb = *reinterpret_cast<const bf16x8*>(&Vts[(db * 16 + lr) * 64 + kc * 32 + lk]);
        acc_o[db] = __builtin_amdgcn_mfma_f32_16x16x32_bf16(pa, vb, acc_o[db], 0, 0, 0);
      }
    }
  }

  // epilogue: y[t][h*64+d] = O/l
  for (int db = 0; db < 4; ++db)
    for (int r = 0; r < 4; ++r) {
      int t = gq + r;
      int d = db * 16 + lr;
      y[(size_t)t * DDIM + h * HDIM + d] = f2bf(acc_o[db][r] / l_r[r]);
    }
}

// ---------------- launch ----------------
extern "C" void kernel_launch(void* const* d_in, const int* in_sizes, int n_in,
                              void* d_out, int out_size, void* d_ws, size_t ws_size,
                              hipStream_t stream) {
  const float* x  = (const float*)d_in[0];
  const float* wq = (const float*)d_in[1];
  const float* wk = (const float*)d_in[2];
  const float* wv = (const float*)d_in[3];
  const float* wo = (const float*)d_in[4];
  float* out = (float*)d_out;
  char* ws = (char*)d_ws;

  unsigned short* xb  = (unsigned short*)(ws + (size_t)0);
  unsigned short* wqb = (unsigned short*)(ws + ((size_t)8  << 20));
  unsigned short* wkb = (unsigned short*)(ws + ((size_t)16 << 20));
  unsigned short* wvb = (unsigned short*)(ws + ((size_t)18 << 20));
  unsigned short* wob = (unsigned short*)(ws + ((size_t)20 << 20));
  float*          qf  = (float*)(ws + ((size_t)28 << 20));
  float*          kf  = (float*)(ws + ((size_t)44 << 20));
  float*          vf  = (float*)(ws + ((size_t)48 << 20));
  unsigned short* qhb = (unsigned short*)(ws + ((size_t)52 << 20));
  unsigned short* khb = (unsigned short*)(ws + ((size_t)60 << 20));
  unsigned short* vtb = (unsigned short*)(ws + ((size_t)62 << 20));
  unsigned short* yb  = (unsigned short*)(ws + ((size_t)64 << 20));

  // casts (element counts /4)
  cast_bf16_kernel<<<4096, 256, 0, stream>>>(x,  xb,  1048576);
  cast_bf16_kernel<<<4096, 256, 0, stream>>>(wq, wqb, 1048576);
  cast_bf16_kernel<<<1024, 256, 0, stream>>>(wk, wkb, 262144);
  cast_bf16_kernel<<<1024, 256, 0, stream>>>(wv, wvb, 262144);
  cast_bf16_kernel<<<4096, 256, 0, stream>>>(wo, wob, 1048576);

  // projections: q = x wq^T, k = x wk^T, v = x wv^T
  gemm_bt_kernel<<<dim3(16, 16), 256, 0, stream>>>(xb, wqb, qf, 2048, 2048, 2048);
  gemm_bt_kernel<<<dim3(16, 4),  256, 0, stream>>>(xb, wkb, kf, 2048, 512, 2048);
  gemm_bt_kernel<<<dim3(16, 4),  256, 0, stream>>>(xb, wvb, vf, 2048, 512, 2048);

  // rope + head-major transpose
  rope_transpose_kernel<<<8192, 256, 0, stream>>>(qf, qhb, 32);
  rope_transpose_kernel<<<2048, 256, 0, stream>>>(kf, khb, 8);
  transpose_v_kernel<<<4096, 256, 0, stream>>>(vf, vtb);

  // attention
  attn_kernel<<<dim3(32, 32), 256, 0, stream>>>(qhb, khb, vtb, yb);

  // out = y wo^T
  gemm_bt_kernel<<<dim3(16, 16), 256, 0, stream>>>(yb, wob, out, 2048, 2048, 2048);
}

// Round 2
// 244.587 us; speedup vs baseline: 1.4816x; 1.4816x over previous
//
#include <hip/hip_runtime.h>
#include <hip/hip_bf16.h>
#include <cstdint>
#include <cstddef>

#define TT 2048
#define DDIM 2048
#define NH 32
#define NKV 8
#define HDIM 64

typedef __attribute__((ext_vector_type(8))) short bf16x8;
typedef __attribute__((ext_vector_type(4))) float f32x4;

__device__ __forceinline__ unsigned short f2bf(float f) {
  unsigned u = __float_as_uint(f);
  unsigned r = 0x7FFFu + ((u >> 16) & 1u);
  return (unsigned short)((u + r) >> 16);
}

__device__ __forceinline__ void gl_lds16(const void* g, void* l) {
  __builtin_amdgcn_global_load_lds(
      (const __attribute__((address_space(1))) void*)g,
      (__attribute__((address_space(3))) void*)l, 16, 0, 0);
}

// ---------------- cast f32 -> bf16 (4-wide) ----------------
__global__ __launch_bounds__(256)
void cast_bf16_kernel(const float* __restrict__ src, unsigned short* __restrict__ dst, int n4) {
  int i = blockIdx.x * 256 + threadIdx.x;
  if (i >= n4) return;
  float4 f = reinterpret_cast<const float4*>(src)[i];
  ushort4 o;
  o.x = f2bf(f.x); o.y = f2bf(f.y); o.z = f2bf(f.z); o.w = f2bf(f.w);
  reinterpret_cast<ushort4*>(dst)[i] = o;
}

// ---------------- GEMM body: C[m][n] = sum_k A[m][k]*B[n][k] ----------------
// 128x128 tile, BK=64, 4 waves (2x2). LDS rows are 64 elems (128B = 8 16B
// granules); XOR-swizzle granule ^= (row&7), applied on the global SOURCE at
// staging (linear LDS dest, rule #21) and on every ds_read address.
__device__ __forceinline__ void gemm_bt_body(
    const unsigned short* __restrict__ A, const unsigned short* __restrict__ B,
    float* __restrict__ C, int N, int K, int bm, int bn,
    unsigned short* As, unsigned short* Bs) {
  const int tid = threadIdx.x;
  const int wave = tid >> 6, lane = tid & 63;
  const int wm = wave >> 1, wn = wave & 1;
  const int lr = lane & 15;
  const int gb = lane >> 4;                    // 0..3 k-granule base for frags
  const int srow = lane >> 3;                  // 0..7 row within 8-row stage blk
  const int scol = (((lane & 7) ^ srow) << 3); // pre-swizzled source col (elems)

  f32x4 acc[4][4];
  for (int i = 0; i < 4; ++i)
    for (int j = 0; j < 4; ++j)
      acc[i][j] = (f32x4){0.f, 0.f, 0.f, 0.f};

  const size_t arow = (size_t)(bm * 128) * K;
  const size_t brow = (size_t)(bn * 128) * K;

  for (int k0 = 0; k0 < K; k0 += 64) {
    __syncthreads();
    for (int i = 0; i < 4; ++i) {
      int blk = wave * 4 + i;                  // 0..15, 8 rows each
      int r = blk * 8 + srow;
      gl_lds16(A + arow + (size_t)r * K + k0 + scol, &As[blk * 8 * 64]);
      gl_lds16(B + brow + (size_t)r * K + k0 + scol, &Bs[blk * 8 * 64]);
    }
    __syncthreads();

    bf16x8 af[2][4], bfr[2][4];
    for (int mi = 0; mi < 4; ++mi) {
      int row = wm * 64 + mi * 16 + lr, sw = row & 7;
      af[0][mi] = *reinterpret_cast<const bf16x8*>(&As[row * 64 + ((gb ^ sw) << 3)]);
      af[1][mi] = *reinterpret_cast<const bf16x8*>(&As[row * 64 + (((4 + gb) ^ sw) << 3)]);
    }
    for (int ni = 0; ni < 4; ++ni) {
      int row = wn * 64 + ni * 16 + lr, sw = row & 7;
      bfr[0][ni] = *reinterpret_cast<const bf16x8*>(&Bs[row * 64 + ((gb ^ sw) << 3)]);
      bfr[1][ni] = *reinterpret_cast<const bf16x8*>(&Bs[row * 64 + (((4 + gb) ^ sw) << 3)]);
    }
    __builtin_amdgcn_s_setprio(1);
    for (int kk = 0; kk < 2; ++kk)
      for (int mi = 0; mi < 4; ++mi)
        for (int ni = 0; ni < 4; ++ni)
          acc[mi][ni] = __builtin_amdgcn_mfma_f32_16x16x32_bf16(af[kk][mi], bfr[kk][ni], acc[mi][ni], 0, 0, 0);
    __builtin_amdgcn_s_setprio(0);
  }

  for (int mi = 0; mi < 4; ++mi)
    for (int ni = 0; ni < 4; ++ni) {
      int col = bn * 128 + wn * 64 + ni * 16 + lr;
      int rbase = bm * 128 + wm * 64 + mi * 16 + (lane >> 4) * 4;
      for (int r = 0; r < 4; ++r)
        C[(size_t)(rbase + r) * N + col] = acc[mi][ni][r];
    }
}

__global__ __launch_bounds__(256)
void gemm_bt_kernel(const unsigned short* __restrict__ A,
                    const unsigned short* __restrict__ B,
                    float* __restrict__ C, int N, int K) {
  __shared__ __align__(16) unsigned short As[128 * 64];
  __shared__ __align__(16) unsigned short Bs[128 * 64];
  gemm_bt_body(A, B, C, N, K, blockIdx.x, blockIdx.y, As, Bs);
}

// fused q/k/v projection: bn 0-15 -> wq/qf, 16-19 -> wk/kf, 20-23 -> wv/vf
__global__ __launch_bounds__(256)
void qkv_gemm_kernel(const unsigned short* __restrict__ xb,
                     const unsigned short* __restrict__ wqb,
                     const unsigned short* __restrict__ wkb,
                     const unsigned short* __restrict__ wvb,
                     float* __restrict__ qf, float* __restrict__ kf,
                     float* __restrict__ vf) {
  __shared__ __align__(16) unsigned short As[128 * 64];
  __shared__ __align__(16) unsigned short Bs[128 * 64];
  int bn = blockIdx.y;
  const unsigned short* B; float* C; int n0, N;
  if (bn < 16)      { B = wqb; C = qf; n0 = bn;      N = 2048; }
  else if (bn < 20) { B = wkb; C = kf; n0 = bn - 16; N = 512;  }
  else              { B = wvb; C = vf; n0 = bn - 20; N = 512;  }
  gemm_bt_body(xb, B, C, N, 2048, blockIdx.x, n0, As, Bs);
}

// ---------------- RoPE + transpose to head-major bf16 ----------------
__global__ __launch_bounds__(256)
void rope_transpose_kernel(const float* __restrict__ src, unsigned short* __restrict__ dst,
                           int nheads) {
  int idx = blockIdx.x * 256 + threadIdx.x;
  int ppt = nheads * 32;
  if (idx >= TT * ppt) return;
  int t = idx / ppt;
  int p = idx - t * ppt;
  int h = p >> 5;
  int i = p & 31;
  float2 q = reinterpret_cast<const float2*>(src)[(size_t)t * ppt + p];
  float theta = exp2f(-(float)(2 * i) * (13.287712379549449f / 64.0f));
  float freq = (float)t * theta;
  float s, c;
  __sincosf(freq, &s, &c);
  float r1 = q.x * c - q.y * s;
  float r2 = q.x * s + q.y * c;
  size_t o = ((size_t)h * TT + t) * HDIM + 2 * i;
  ushort2 ov; ov.x = f2bf(r1); ov.y = f2bf(r2);
  *reinterpret_cast<ushort2*>(&dst[o]) = ov;
}

// ---------------- V transpose: [T][512] f32 -> [8][64][T] bf16 ----------------
__global__ __launch_bounds__(256)
void transpose_v_kernel(const float* __restrict__ src, unsigned short* __restrict__ dst) {
  int idx = blockIdx.x * 256 + threadIdx.x;
  if (idx >= 512 * TT) return;
  int t = idx & (TT - 1);
  int c = idx >> 11;
  dst[idx] = f2bf(src[(size_t)t * 512 + c]);
}

// ---------------- flash attention (GQA, causal) ----------------
// All LDS tiles are [rows][64] bf16 (128B rows, 8 granules): swizzled
// granule ^= row&7 -- staged via pre-swizzled global source (K,Vt) or
// swizzled element writes (P), read with the same XOR.
__global__ __launch_bounds__(256)
void attn_kernel(const unsigned short* __restrict__ qh,
                 const unsigned short* __restrict__ kh,
                 const unsigned short* __restrict__ vt,
                 unsigned short* __restrict__ y) {
  __shared__ __align__(16) unsigned short Ks[64 * 64];
  __shared__ __align__(16) unsigned short Vts[64 * 64];
  __shared__ __align__(16) unsigned short Ps[4][16 * 64];
  const int qb = (int)(gridDim.x - 1) - (int)blockIdx.x;  // heavy blocks first
  const int h = blockIdx.y, hkv = h >> 2;
  const int tid = threadIdx.x, wave = tid >> 6, lane = tid & 63;
  const int lr = lane & 15, gbq = lane >> 4, lk = gbq * 8;
  const int srow = lane >> 3;
  const int scol = (((lane & 7) ^ srow) << 3);

  bf16x8 qa[2];
  {
    const unsigned short* qbase = qh + ((size_t)h * TT + qb * 64 + wave * 16 + lr) * HDIM;
    qa[0] = *reinterpret_cast<const bf16x8*>(qbase + lk);
    qa[1] = *reinterpret_cast<const bf16x8*>(qbase + 32 + lk);
  }

  f32x4 acc_o[4];
  for (int i = 0; i < 4; ++i) acc_o[i] = (f32x4){0.f, 0.f, 0.f, 0.f};
  float m_r[4], l_r[4];
  for (int r = 0; r < 4; ++r) { m_r[r] = -1e30f; l_r[r] = 0.f; }
  const int gq = qb * 64 + wave * 16 + gbq * 4;

  for (int jb = 0; jb <= qb; ++jb) {
    __syncthreads();
    for (int i = 0; i < 2; ++i) {
      int rblk = wave * 2 + i;
      int r = rblk * 8 + srow;
      gl_lds16(kh + ((size_t)hkv * TT + jb * 64 + r) * HDIM + scol, &Ks[rblk * 8 * 64]);
      gl_lds16(vt + ((size_t)(hkv * HDIM + r)) * TT + jb * 64 + scol, &Vts[rblk * 8 * 64]);
    }
    __syncthreads();

    f32x4 s[4];
    for (int ni = 0; ni < 4; ++ni) s[ni] = (f32x4){0.f, 0.f, 0.f, 0.f};
    __builtin_amdgcn_s_setprio(1);
    for (int ni = 0; ni < 4; ++ni) {
      int row = ni * 16 + lr, sw = row & 7;
      bf16x8 kb0 = *reinterpret_cast<const bf16x8*>(&Ks[row * 64 + ((gbq ^ sw) << 3)]);
      bf16x8 kb1 = *reinterpret_cast<const bf16x8*>(&Ks[row * 64 + (((4 + gbq) ^ sw) << 3)]);
      s[ni] = __builtin_amdgcn_mfma_f32_16x16x32_bf16(qa[0], kb0, s[ni], 0, 0, 0);
      s[ni] = __builtin_amdgcn_mfma_f32_16x16x32_bf16(qa[1], kb1, s[ni], 0, 0, 0);
    }
    __builtin_amdgcn_s_setprio(0);

    for (int ni = 0; ni < 4; ++ni) {
      int jg = jb * 64 + ni * 16 + lr;
      for (int r = 0; r < 4; ++r) {
        float v = s[ni][r] * 0.125f;
        s[ni][r] = (jg <= gq + r) ? v : -1e30f;
      }
    }
    float alpha[4];
    for (int r = 0; r < 4; ++r) {
      float mx = fmaxf(fmaxf(s[0][r], s[1][r]), fmaxf(s[2][r], s[3][r]));
      for (int off = 1; off < 16; off <<= 1) mx = fmaxf(mx, __shfl_xor(mx, off));
      float mn = fmaxf(m_r[r], mx);
      alpha[r] = __expf(m_r[r] - mn);
      m_r[r] = mn;
    }
    float rs[4] = {0.f, 0.f, 0.f, 0.f};
    for (int ni = 0; ni < 4; ++ni)
      for (int r = 0; r < 4; ++r) {
        float p = __expf(s[ni][r] - m_r[r]);
        s[ni][r] = p;
        rs[r] += p;
      }
    for (int r = 0; r < 4; ++r) {
      for (int off = 1; off < 16; off <<= 1) rs[r] += __shfl_xor(rs[r], off);
      l_r[r] = l_r[r] * alpha[r] + rs[r];
    }
    for (int db = 0; db < 4; ++db)
      for (int r = 0; r < 4; ++r) acc_o[db][r] *= alpha[r];

    // P -> LDS (bf16), swizzled element writes
    for (int ni = 0; ni < 4; ++ni)
      for (int r = 0; r < 4; ++r) {
        int rr = gbq * 4 + r;
        int col = ni * 16 + lr;
        Ps[wave][rr * 64 + (col ^ ((rr & 7) << 3))] = f2bf(s[ni][r]);
      }
    asm volatile("s_waitcnt lgkmcnt(0)" ::: "memory");
    __builtin_amdgcn_sched_barrier(0);

    // O += P V
    for (int kc = 0; kc < 2; ++kc) {
      int g = kc * 4 + gbq;
      bf16x8 pa = *reinterpret_cast<const bf16x8*>(&Ps[wave][lr * 64 + ((g ^ (lr & 7)) << 3)]);
      __builtin_amdgcn_s_setprio(1);
      for (int db = 0; db < 4; ++db) {
        int row = db * 16 + lr, sw = row & 7;
        bf16x8 vb = *reinterpret_cast<const bf16x8*>(&Vts[row * 64 + ((g ^ sw) << 3)]);
        acc_o[db] = __builtin_amdgcn_mfma_f32_16x16x32_bf16(pa, vb, acc_o[db], 0, 0, 0);
      }
      __builtin_amdgcn_s_setprio(0);
    }
  }

  for (int db = 0; db < 4; ++db)
    for (int r = 0; r < 4; ++r) {
      int t = gq + r;
      int d = db * 16 + lr;
      y[(size_t)t * DDIM + h * HDIM + d] = f2bf(acc_o[db][r] / l_r[r]);
    }
}

// ---------------- launch ----------------
extern "C" void kernel_launch(void* const* d_in, const int* in_sizes, int n_in,
                              void* d_out, int out_size, void* d_ws, size_t ws_size,
                              hipStream_t stream) {
  const float* x  = (const float*)d_in[0];
  const float* wq = (const float*)d_in[1];
  const float* wk = (const float*)d_in[2];
  const float* wv = (const float*)d_in[3];
  const float* wo = (const float*)d_in[4];
  float* out = (float*)d_out;
  char* ws = (char*)d_ws;

  unsigned short* xb  = (unsigned short*)(ws + (size_t)0);
  unsigned short* wqb = (unsigned short*)(ws + ((size_t)8  << 20));
  unsigned short* wkb = (unsigned short*)(ws + ((size_t)16 << 20));
  unsigned short* wvb = (unsigned short*)(ws + ((size_t)18 << 20));
  unsigned short* wob = (unsigned short*)(ws + ((size_t)20 << 20));
  float*          qf  = (float*)(ws + ((size_t)28 << 20));
  float*          kf  = (float*)(ws + ((size_t)44 << 20));
  float*          vf  = (float*)(ws + ((size_t)48 << 20));
  unsigned short* qhb = (unsigned short*)(ws + ((size_t)52 << 20));
  unsigned short* khb = (unsigned short*)(ws + ((size_t)60 << 20));
  unsigned short* vtb = (unsigned short*)(ws + ((size_t)62 << 20));
  unsigned short* yb  = (unsigned short*)(ws + ((size_t)64 << 20));

  cast_bf16_kernel<<<4096, 256, 0, stream>>>(x,  xb,  1048576);
  cast_bf16_kernel<<<4096, 256, 0, stream>>>(wq, wqb, 1048576);
  cast_bf16_kernel<<<1024, 256, 0, stream>>>(wk, wkb, 262144);
  cast_bf16_kernel<<<1024, 256, 0, stream>>>(wv, wvb, 262144);
  cast_bf16_kernel<<<4096, 256, 0, stream>>>(wo, wob, 1048576);

  qkv_gemm_kernel<<<dim3(16, 24), 256, 0, stream>>>(xb, wqb, wkb, wvb, qf, kf, vf);

  rope_transpose_kernel<<<8192, 256, 0, stream>>>(qf, qhb, 32);
  rope_transpose_kernel<<<2048, 256, 0, stream>>>(kf, khb, 8);
  transpose_v_kernel<<<4096, 256, 0, stream>>>(vf, vtb);

  attn_kernel<<<dim3(32, 32), 256, 0, stream>>>(qhb, khb, vtb, yb);

  gemm_bt_kernel<<<dim3(16, 16), 256, 0, stream>>>(yb, wob, out, 2048, 2048);
}

// Round 3
// 231.154 us; speedup vs baseline: 1.5677x; 1.0581x over previous
//
#include <hip/hip_runtime.h>
#include <hip/hip_bf16.h>
#include <cstdint>
#include <cstddef>

#define TT 2048
#define DDIM 2048
#define NH 32
#define NKV 8
#define HDIM 64

typedef __attribute__((ext_vector_type(8))) short bf16x8;
typedef __attribute__((ext_vector_type(4))) float f32x4;

__device__ __forceinline__ unsigned short f2bf(float f) {
  unsigned u = __float_as_uint(f);
  unsigned r = 0x7FFFu + ((u >> 16) & 1u);
  return (unsigned short)((u + r) >> 16);
}

__device__ __forceinline__ void gl_lds16(const void* g, void* l) {
  __builtin_amdgcn_global_load_lds(
      (const __attribute__((address_space(1))) void*)g,
      (__attribute__((address_space(3))) void*)l, 16, 0, 0);
}

// ---------------- fused cast f32 -> bf16 (4-wide, 5 segments) ----------------
__global__ __launch_bounds__(256)
void cast5_kernel(const float* __restrict__ x, const float* __restrict__ wq,
                  const float* __restrict__ wk, const float* __restrict__ wv,
                  const float* __restrict__ wo,
                  unsigned short* __restrict__ xb, unsigned short* __restrict__ wqb,
                  unsigned short* __restrict__ wkb, unsigned short* __restrict__ wvb,
                  unsigned short* __restrict__ wob) {
  int i = blockIdx.x * 256 + threadIdx.x;  // float4 index, total 3670016
  const float* s; unsigned short* d; int off;
  if (i < 1048576)      { s = x;  d = xb;  off = i; }
  else if (i < 2097152) { s = wq; d = wqb; off = i - 1048576; }
  else if (i < 2359296) { s = wk; d = wkb; off = i - 2097152; }
  else if (i < 2621440) { s = wv; d = wvb; off = i - 2359296; }
  else                  { s = wo; d = wob; off = i - 2621440; }
  float4 f = reinterpret_cast<const float4*>(s)[off];
  ushort4 o;
  o.x = f2bf(f.x); o.y = f2bf(f.y); o.z = f2bf(f.z); o.w = f2bf(f.w);
  reinterpret_cast<ushort4*>(d)[off] = o;
}

// ---------------- GEMM body: C[m][n] = sum_k A[m][k]*B[n][k] ----------------
// 128x128 tile, BK=64, 4 waves (2x2), double-buffered LDS, 2-phase pipeline:
// issue next-tile global_load_lds BEFORE compute, drain (inside syncthreads)
// AFTER compute. XOR-swizzle granule^=(row&7): pre-swizzled global source at
// staging (linear LDS dest), same XOR on ds_read.
__device__ __forceinline__ void gemm_bt_body(
    const unsigned short* __restrict__ A, const unsigned short* __restrict__ B,
    float* __restrict__ C, int N, int K, int bm, int bn,
    unsigned short (*As)[128 * 64], unsigned short (*Bs)[128 * 64]) {
  const int tid = threadIdx.x;
  const int wave = tid >> 6, lane = tid & 63;
  const int wm = wave >> 1, wn = wave & 1;
  const int lr = lane & 15;
  const int gb = lane >> 4;
  const int srow = lane >> 3;
  const int scol = (((lane & 7) ^ srow) << 3);

  f32x4 acc[4][4];
  for (int i = 0; i < 4; ++i)
    for (int j = 0; j < 4; ++j)
      acc[i][j] = (f32x4){0.f, 0.f, 0.f, 0.f};

  const size_t arow = (size_t)(bm * 128) * K;
  const size_t brow = (size_t)(bn * 128) * K;

#define G_STAGE(buf, k0)                                                      \
  for (int i = 0; i < 4; ++i) {                                               \
    int blk = wave * 4 + i;                                                   \
    int r = blk * 8 + srow;                                                   \
    gl_lds16(A + arow + (size_t)r * K + (k0) + scol, &As[buf][blk * 8 * 64]); \
    gl_lds16(B + brow + (size_t)r * K + (k0) + scol, &Bs[buf][blk * 8 * 64]); \
  }

  const int nt = K >> 6;
  G_STAGE(0, 0)
  __syncthreads();
  int cur = 0;
  for (int t = 0; t < nt; ++t) {
    if (t + 1 < nt) { G_STAGE(cur ^ 1, (t + 1) << 6) }

    bf16x8 af[2][4], bfr[2][4];
    for (int mi = 0; mi < 4; ++mi) {
      int row = wm * 64 + mi * 16 + lr, sw = row & 7;
      af[0][mi] = *reinterpret_cast<const bf16x8*>(&As[cur][row * 64 + ((gb ^ sw) << 3)]);
      af[1][mi] = *reinterpret_cast<const bf16x8*>(&As[cur][row * 64 + (((4 + gb) ^ sw) << 3)]);
    }
    for (int ni = 0; ni < 4; ++ni) {
      int row = wn * 64 + ni * 16 + lr, sw = row & 7;
      bfr[0][ni] = *reinterpret_cast<const bf16x8*>(&Bs[cur][row * 64 + ((gb ^ sw) << 3)]);
      bfr[1][ni] = *reinterpret_cast<const bf16x8*>(&Bs[cur][row * 64 + (((4 + gb) ^ sw) << 3)]);
    }
    __builtin_amdgcn_s_setprio(1);
    for (int kk = 0; kk < 2; ++kk)
      for (int mi = 0; mi < 4; ++mi)
        for (int ni = 0; ni < 4; ++ni)
          acc[mi][ni] = __builtin_amdgcn_mfma_f32_16x16x32_bf16(af[kk][mi], bfr[kk][ni], acc[mi][ni], 0, 0, 0);
    __builtin_amdgcn_s_setprio(0);
    __syncthreads();  // drains just-issued stage loads (they had the whole compute phase)
    cur ^= 1;
  }
#undef G_STAGE

  for (int mi = 0; mi < 4; ++mi)
    for (int ni = 0; ni < 4; ++ni) {
      int col = bn * 128 + wn * 64 + ni * 16 + lr;
      int rbase = bm * 128 + wm * 64 + mi * 16 + (lane >> 4) * 4;
      for (int r = 0; r < 4; ++r)
        C[(size_t)(rbase + r) * N + col] = acc[mi][ni][r];
    }
}

__global__ __launch_bounds__(256)
void gemm_bt_kernel(const unsigned short* __restrict__ A,
                    const unsigned short* __restrict__ B,
                    float* __restrict__ C, int N, int K) {
  __shared__ __align__(16) unsigned short As[2][128 * 64];
  __shared__ __align__(16) unsigned short Bs[2][128 * 64];
  gemm_bt_body(A, B, C, N, K, blockIdx.x, blockIdx.y, As, Bs);
}

// fused q/k/v projection: bn 0-15 -> wq/qf, 16-19 -> wk/kf, 20-23 -> wv/vf
__global__ __launch_bounds__(256)
void qkv_gemm_kernel(const unsigned short* __restrict__ xb,
                     const unsigned short* __restrict__ wqb,
                     const unsigned short* __restrict__ wkb,
                     const unsigned short* __restrict__ wvb,
                     float* __restrict__ qf, float* __restrict__ kf,
                     float* __restrict__ vf) {
  __shared__ __align__(16) unsigned short As[2][128 * 64];
  __shared__ __align__(16) unsigned short Bs[2][128 * 64];
  int bn = blockIdx.y;
  const unsigned short* B; float* C; int n0, N;
  if (bn < 16)      { B = wqb; C = qf; n0 = bn;      N = 2048; }
  else if (bn < 20) { B = wkb; C = kf; n0 = bn - 16; N = 512;  }
  else              { B = wvb; C = vf; n0 = bn - 20; N = 512;  }
  gemm_bt_body(xb, B, C, N, 2048, blockIdx.x, n0, As, Bs);
}

// ---------------- RoPE + transpose to head-major bf16 ----------------
// src: [T][nheads*64] f32 ; dst: [nheads][T][64] bf16 ; scale folded in (q: 1/8)
__global__ __launch_bounds__(256)
void rope_transpose_kernel(const float* __restrict__ src, unsigned short* __restrict__ dst,
                           int pptShift, float scale) {
  int idx = blockIdx.x * 256 + threadIdx.x;
  int ppt = 1 << pptShift;
  if (idx >= (TT << pptShift)) return;
  int t = idx >> pptShift;
  int p = idx & (ppt - 1);
  int h = p >> 5;
  int i = p & 31;
  float2 q = reinterpret_cast<const float2*>(src)[(size_t)t * ppt + p];
  float theta = exp2f(-(float)(2 * i) * (13.287712379549449f / 64.0f));
  float freq = (float)t * theta;
  float s, c;
  __sincosf(freq, &s, &c);
  float r1 = (q.x * c - q.y * s) * scale;
  float r2 = (q.x * s + q.y * c) * scale;
  size_t o = ((size_t)h * TT + t) * HDIM + 2 * i;
  ushort2 ov; ov.x = f2bf(r1); ov.y = f2bf(r2);
  *reinterpret_cast<ushort2*>(&dst[o]) = ov;
}

// ---------------- V transpose: [T][512] f32 -> [8][64][T] bf16 ----------------
__global__ __launch_bounds__(256)
void transpose_v_kernel(const float* __restrict__ src, unsigned short* __restrict__ dst) {
  int idx = blockIdx.x * 256 + threadIdx.x;
  if (idx >= 512 * TT) return;
  int t = idx & (TT - 1);
  int c = idx >> 11;
  dst[idx] = f2bf(src[(size_t)t * 512 + c]);
}

// ---------------- flash attention (GQA, causal) ----------------
// Double-buffered K/Vt tiles, 2-phase pipeline (stage next -> compute cur ->
// barrier). All LDS tiles [rows][64] bf16 with granule^=(row&7) swizzle.
// Q pre-scaled by 1/8 in rope; only the diagonal tile is masked.
__global__ __launch_bounds__(256)
void attn_kernel(const unsigned short* __restrict__ qh,
                 const unsigned short* __restrict__ kh,
                 const unsigned short* __restrict__ vt,
                 unsigned short* __restrict__ y) {
  __shared__ __align__(16) unsigned short Ks[2][64 * 64];
  __shared__ __align__(16) unsigned short Vts[2][64 * 64];
  __shared__ __align__(16) unsigned short Ps[4][16 * 64];
  const int qb = (int)(gridDim.x - 1) - (int)blockIdx.x;  // heavy blocks first
  const int h = blockIdx.y, hkv = h >> 2;
  const int tid = threadIdx.x, wave = tid >> 6, lane = tid & 63;
  const int lr = lane & 15, gbq = lane >> 4, lk = gbq * 8;
  const int srow = lane >> 3;
  const int scol = (((lane & 7) ^ srow) << 3);

  bf16x8 qa[2];
  {
    const unsigned short* qbase = qh + ((size_t)h * TT + qb * 64 + wave * 16 + lr) * HDIM;
    qa[0] = *reinterpret_cast<const bf16x8*>(qbase + lk);
    qa[1] = *reinterpret_cast<const bf16x8*>(qbase + 32 + lk);
  }

  f32x4 acc_o[4];
  for (int i = 0; i < 4; ++i) acc_o[i] = (f32x4){0.f, 0.f, 0.f, 0.f};
  float m_r[4], l_r[4];
  for (int r = 0; r < 4; ++r) { m_r[r] = -1e30f; l_r[r] = 0.f; }
  const int gq = qb * 64 + wave * 16 + gbq * 4;

#define A_STAGE(buf, jb)                                                            \
  for (int i = 0; i < 2; ++i) {                                                     \
    int rblk = wave * 2 + i;                                                        \
    int r = rblk * 8 + srow;                                                        \
    gl_lds16(kh + ((size_t)hkv * TT + (jb) * 64 + r) * HDIM + scol,                 \
             &Ks[buf][rblk * 8 * 64]);                                              \
    gl_lds16(vt + ((size_t)(hkv * HDIM + r)) * TT + (jb) * 64 + scol,               \
             &Vts[buf][rblk * 8 * 64]);                                             \
  }

  A_STAGE(0, 0)
  __syncthreads();
  int cur = 0;

  for (int jb = 0; jb <= qb; ++jb) {
    if (jb < qb) { A_STAGE(cur ^ 1, jb + 1) }

    f32x4 s[4];
    for (int ni = 0; ni < 4; ++ni) s[ni] = (f32x4){0.f, 0.f, 0.f, 0.f};
    __builtin_amdgcn_s_setprio(1);
    for (int ni = 0; ni < 4; ++ni) {
      int row = ni * 16 + lr, sw = row & 7;
      bf16x8 kb0 = *reinterpret_cast<const bf16x8*>(&Ks[cur][row * 64 + ((gbq ^ sw) << 3)]);
      bf16x8 kb1 = *reinterpret_cast<const bf16x8*>(&Ks[cur][row * 64 + (((4 + gbq) ^ sw) << 3)]);
      s[ni] = __builtin_amdgcn_mfma_f32_16x16x32_bf16(qa[0], kb0, s[ni], 0, 0, 0);
      s[ni] = __builtin_amdgcn_mfma_f32_16x16x32_bf16(qa[1], kb1, s[ni], 0, 0, 0);
    }
    __builtin_amdgcn_s_setprio(0);

    if (jb == qb) {  // diagonal tile: causal mask
      for (int ni = 0; ni < 4; ++ni) {
        int jg = jb * 64 + ni * 16 + lr;
        for (int r = 0; r < 4; ++r)
          if (jg > gq + r) s[ni][r] = -1e30f;
      }
    }
    float alpha[4];
    for (int r = 0; r < 4; ++r) {
      float mx = fmaxf(fmaxf(s[0][r], s[1][r]), fmaxf(s[2][r], s[3][r]));
      for (int off = 1; off < 16; off <<= 1) mx = fmaxf(mx, __shfl_xor(mx, off));
      float mn = fmaxf(m_r[r], mx);
      alpha[r] = __expf(m_r[r] - mn);
      m_r[r] = mn;
    }
    float rs[4] = {0.f, 0.f, 0.f, 0.f};
    for (int ni = 0; ni < 4; ++ni)
      for (int r = 0; r < 4; ++r) {
        float p = __expf(s[ni][r] - m_r[r]);
        s[ni][r] = p;
        rs[r] += p;
      }
    for (int r = 0; r < 4; ++r) {
      for (int off = 1; off < 16; off <<= 1) rs[r] += __shfl_xor(rs[r], off);
      l_r[r] = l_r[r] * alpha[r] + rs[r];
    }
    for (int db = 0; db < 4; ++db)
      for (int r = 0; r < 4; ++r) acc_o[db][r] *= alpha[r];

    for (int ni = 0; ni < 4; ++ni)
      for (int r = 0; r < 4; ++r) {
        int rr = gbq * 4 + r;
        int col = ni * 16 + lr;
        Ps[wave][rr * 64 + (col ^ ((rr & 7) << 3))] = f2bf(s[ni][r]);
      }
    asm volatile("s_waitcnt lgkmcnt(0)" ::: "memory");
    __builtin_amdgcn_sched_barrier(0);

    for (int kc = 0; kc < 2; ++kc) {
      int g = kc * 4 + gbq;
      bf16x8 pa = *reinterpret_cast<const bf16x8*>(&Ps[wave][lr * 64 + ((g ^ (lr & 7)) << 3)]);
      __builtin_amdgcn_s_setprio(1);
      for (int db = 0; db < 4; ++db) {
        int row = db * 16 + lr, sw = row & 7;
        bf16x8 vb = *reinterpret_cast<const bf16x8*>(&Vts[cur][row * 64 + ((g ^ sw) << 3)]);
        acc_o[db] = __builtin_amdgcn_mfma_f32_16x16x32_bf16(pa, vb, acc_o[db], 0, 0, 0);
      }
      __builtin_amdgcn_s_setprio(0);
    }
    __syncthreads();  // drains stage loads for jb+1; frees buf[cur] for overwrite
    cur ^= 1;
  }
#undef A_STAGE

  for (int db = 0; db < 4; ++db)
    for (int r = 0; r < 4; ++r) {
      int t = gq + r;
      int d = db * 16 + lr;
      y[(size_t)t * DDIM + h * HDIM + d] = f2bf(acc_o[db][r] / l_r[r]);
    }
}

// ---------------- launch ----------------
extern "C" void kernel_launch(void* const* d_in, const int* in_sizes, int n_in,
                              void* d_out, int out_size, void* d_ws, size_t ws_size,
                              hipStream_t stream) {
  const float* x  = (const float*)d_in[0];
  const float* wq = (const float*)d_in[1];
  const float* wk = (const float*)d_in[2];
  const float* wv = (const float*)d_in[3];
  const float* wo = (const float*)d_in[4];
  float* out = (float*)d_out;
  char* ws = (char*)d_ws;

  unsigned short* xb  = (unsigned short*)(ws + (size_t)0);
  unsigned short* wqb = (unsigned short*)(ws + ((size_t)8  << 20));
  unsigned short* wkb = (unsigned short*)(ws + ((size_t)16 << 20));
  unsigned short* wvb = (unsigned short*)(ws + ((size_t)18 << 20));
  unsigned short* wob = (unsigned short*)(ws + ((size_t)20 << 20));
  float*          qf  = (float*)(ws + ((size_t)28 << 20));
  float*          kf  = (float*)(ws + ((size_t)44 << 20));
  float*          vf  = (float*)(ws + ((size_t)48 << 20));
  unsigned short* qhb = (unsigned short*)(ws + ((size_t)52 << 20));
  unsigned short* khb = (unsigned short*)(ws + ((size_t)60 << 20));
  unsigned short* vtb = (unsigned short*)(ws + ((size_t)62 << 20));
  unsigned short* yb  = (unsigned short*)(ws + ((size_t)64 << 20));

  cast5_kernel<<<14336, 256, 0, stream>>>(x, wq, wk, wv, wo, xb, wqb, wkb, wvb, wob);

  qkv_gemm_kernel<<<dim3(16, 24), 256, 0, stream>>>(xb, wqb, wkb, wvb, qf, kf, vf);

  rope_transpose_kernel<<<8192, 256, 0, stream>>>(qf, qhb, 10, 0.125f);
  rope_transpose_kernel<<<2048, 256, 0, stream>>>(kf, khb, 8, 1.0f);
  transpose_v_kernel<<<4096, 256, 0, stream>>>(vf, vtb);

  attn_kernel<<<dim3(32, 32), 256, 0, stream>>>(qhb, khb, vtb, yb);

  gemm_bt_kernel<<<dim3(16, 16), 256, 0, stream>>>(yb, wob, out, 2048, 2048);
}

// Round 5
// 159.769 us; speedup vs baseline: 2.2681x; 1.4468x over previous
//
#include <hip/hip_runtime.h>
#include <hip/hip_bf16.h>
#include <cstdint>
#include <cstddef>

#define TT 2048
#define DDIM 2048
#define NH 32
#define NKV 8
#define HDIM 64

typedef __attribute__((ext_vector_type(8))) short bf16x8;
typedef __attribute__((ext_vector_type(4))) float f32x4;
typedef __attribute__((ext_vector_type(16))) float f32x16;

__device__ __forceinline__ unsigned short f2bf(float f) {
  unsigned u = __float_as_uint(f);
  unsigned r = 0x7FFFu + ((u >> 16) & 1u);
  return (unsigned short)((u + r) >> 16);
}

__device__ __forceinline__ void gl_lds16(const void* g, void* l) {
  __builtin_amdgcn_global_load_lds(
      (const __attribute__((address_space(1))) void*)g,
      (__attribute__((address_space(3))) void*)l, 16, 0, 0);
}

__device__ __forceinline__ unsigned pkbf(float lo, float hi) {
  unsigned r;
  asm("v_cvt_pk_bf16_f32 %0, %1, %2" : "=v"(r) : "v"(lo), "v"(hi));
  return r;
}
// v_permlane32_swap_b32 dst, src:
//   new_dst[l<32]=dst[l], new_dst[l>=32]=src[l-32]
//   new_src[l<32]=dst[l+32], new_src[l>=32]=src[l]
__device__ __forceinline__ void swap32(unsigned& dst, unsigned& src) {
  asm volatile("v_permlane32_swap_b32 %0, %1" : "+v"(dst), "+v"(src));
}
union W4 { unsigned w[4]; bf16x8 v; };

// ---------------- fused cast f32 -> bf16 (4-wide, 5 segments) ----------------
__global__ __launch_bounds__(256)
void cast5_kernel(const float* __restrict__ x, const float* __restrict__ wq,
                  const float* __restrict__ wk, const float* __restrict__ wv,
                  const float* __restrict__ wo,
                  unsigned short* __restrict__ xb, unsigned short* __restrict__ wqb,
                  unsigned short* __restrict__ wkb, unsigned short* __restrict__ wvb,
                  unsigned short* __restrict__ wob) {
  int i = blockIdx.x * 256 + threadIdx.x;
  const float* s; unsigned short* d; int off;
  if (i < 1048576)      { s = x;  d = xb;  off = i; }
  else if (i < 2097152) { s = wq; d = wqb; off = i - 1048576; }
  else if (i < 2359296) { s = wk; d = wkb; off = i - 2097152; }
  else if (i < 2621440) { s = wv; d = wvb; off = i - 2359296; }
  else                  { s = wo; d = wob; off = i - 2621440; }
  float4 f = reinterpret_cast<const float4*>(s)[off];
  ushort4 o;
  o.x = f2bf(f.x); o.y = f2bf(f.y); o.z = f2bf(f.z); o.w = f2bf(f.w);
  reinterpret_cast<ushort4*>(d)[off] = o;
}

// ---------------- GEMM body (unchanged from R3) ----------------
__device__ __forceinline__ void gemm_bt_body(
    const unsigned short* __restrict__ A, const unsigned short* __restrict__ B,
    float* __restrict__ C, int N, int K, int bm, int bn,
    unsigned short (*As)[128 * 64], unsigned short (*Bs)[128 * 64]) {
  const int tid = threadIdx.x;
  const int wave = tid >> 6, lane = tid & 63;
  const int wm = wave >> 1, wn = wave & 1;
  const int lr = lane & 15;
  const int gb = lane >> 4;
  const int srow = lane >> 3;
  const int scol = (((lane & 7) ^ srow) << 3);

  f32x4 acc[4][4];
  for (int i = 0; i < 4; ++i)
    for (int j = 0; j < 4; ++j)
      acc[i][j] = (f32x4){0.f, 0.f, 0.f, 0.f};

  const size_t arow = (size_t)(bm * 128) * K;
  const size_t brow = (size_t)(bn * 128) * K;

#define G_STAGE(buf, k0)                                                      \
  for (int i = 0; i < 4; ++i) {                                               \
    int blk = wave * 4 + i;                                                   \
    int r = blk * 8 + srow;                                                   \
    gl_lds16(A + arow + (size_t)r * K + (k0) + scol, &As[buf][blk * 8 * 64]); \
    gl_lds16(B + brow + (size_t)r * K + (k0) + scol, &Bs[buf][blk * 8 * 64]); \
  }

  const int nt = K >> 6;
  G_STAGE(0, 0)
  __syncthreads();
  int cur = 0;
  for (int t = 0; t < nt; ++t) {
    if (t + 1 < nt) { G_STAGE(cur ^ 1, (t + 1) << 6) }

    bf16x8 af[2][4], bfr[2][4];
    for (int mi = 0; mi < 4; ++mi) {
      int row = wm * 64 + mi * 16 + lr, sw = row & 7;
      af[0][mi] = *reinterpret_cast<const bf16x8*>(&As[cur][row * 64 + ((gb ^ sw) << 3)]);
      af[1][mi] = *reinterpret_cast<const bf16x8*>(&As[cur][row * 64 + (((4 + gb) ^ sw) << 3)]);
    }
    for (int ni = 0; ni < 4; ++ni) {
      int row = wn * 64 + ni * 16 + lr, sw = row & 7;
      bfr[0][ni] = *reinterpret_cast<const bf16x8*>(&Bs[cur][row * 64 + ((gb ^ sw) << 3)]);
      bfr[1][ni] = *reinterpret_cast<const bf16x8*>(&Bs[cur][row * 64 + (((4 + gb) ^ sw) << 3)]);
    }
    __builtin_amdgcn_s_setprio(1);
    for (int kk = 0; kk < 2; ++kk)
      for (int mi = 0; mi < 4; ++mi)
        for (int ni = 0; ni < 4; ++ni)
          acc[mi][ni] = __builtin_amdgcn_mfma_f32_16x16x32_bf16(af[kk][mi], bfr[kk][ni], acc[mi][ni], 0, 0, 0);
    __builtin_amdgcn_s_setprio(0);
    __syncthreads();
    cur ^= 1;
  }
#undef G_STAGE

  for (int mi = 0; mi < 4; ++mi)
    for (int ni = 0; ni < 4; ++ni) {
      int col = bn * 128 + wn * 64 + ni * 16 + lr;
      int rbase = bm * 128 + wm * 64 + mi * 16 + (lane >> 4) * 4;
      for (int r = 0; r < 4; ++r)
        C[(size_t)(rbase + r) * N + col] = acc[mi][ni][r];
    }
}

__global__ __launch_bounds__(256)
void gemm_bt_kernel(const unsigned short* __restrict__ A,
                    const unsigned short* __restrict__ B,
                    float* __restrict__ C, int N, int K) {
  __shared__ __align__(16) unsigned short As[2][128 * 64];
  __shared__ __align__(16) unsigned short Bs[2][128 * 64];
  gemm_bt_body(A, B, C, N, K, blockIdx.x, blockIdx.y, As, Bs);
}

__global__ __launch_bounds__(256)
void qkv_gemm_kernel(const unsigned short* __restrict__ xb,
                     const unsigned short* __restrict__ wqb,
                     const unsigned short* __restrict__ wkb,
                     const unsigned short* __restrict__ wvb,
                     float* __restrict__ qf, float* __restrict__ kf,
                     float* __restrict__ vf) {
  __shared__ __align__(16) unsigned short As[2][128 * 64];
  __shared__ __align__(16) unsigned short Bs[2][128 * 64];
  int bn = blockIdx.y;
  const unsigned short* B; float* C; int n0, N;
  if (bn < 16)      { B = wqb; C = qf; n0 = bn;      N = 2048; }
  else if (bn < 20) { B = wkb; C = kf; n0 = bn - 16; N = 512;  }
  else              { B = wvb; C = vf; n0 = bn - 20; N = 512;  }
  gemm_bt_body(xb, B, C, N, 2048, blockIdx.x, n0, As, Bs);
}

// ---------------- RoPE + transpose to head-major bf16 ----------------
__global__ __launch_bounds__(256)
void rope_transpose_kernel(const float* __restrict__ src, unsigned short* __restrict__ dst,
                           int pptShift, float scale) {
  int idx = blockIdx.x * 256 + threadIdx.x;
  int ppt = 1 << pptShift;
  if (idx >= (TT << pptShift)) return;
  int t = idx >> pptShift;
  int p = idx & (ppt - 1);
  int h = p >> 5;
  int i = p & 31;
  float2 q = reinterpret_cast<const float2*>(src)[(size_t)t * ppt + p];
  float theta = exp2f(-(float)(2 * i) * (13.287712379549449f / 64.0f));
  float freq = (float)t * theta;
  float s, c;
  __sincosf(freq, &s, &c);
  float r1 = (q.x * c - q.y * s) * scale;
  float r2 = (q.x * s + q.y * c) * scale;
  size_t o = ((size_t)h * TT + t) * HDIM + 2 * i;
  ushort2 ov; ov.x = f2bf(r1); ov.y = f2bf(r2);
  *reinterpret_cast<ushort2*>(&dst[o]) = ov;
}

// ------- V transpose via LDS tile: [T][512] f32 -> [8][64][T] bf16 -------
__global__ __launch_bounds__(256)
void transpose_v_kernel(const float* __restrict__ src, unsigned short* __restrict__ dst) {
  __shared__ float L[64][65];
  const int tb = blockIdx.x & 31;   // t tile
  const int cb = blockIdx.x >> 5;   // c tile
  const int tid = threadIdx.x;
  const int r = tid >> 2;
  const int cg = (tid & 3) * 16;
  const float* s = src + (size_t)(tb * 64 + r) * 512 + cb * 64 + cg;
#pragma unroll
  for (int k = 0; k < 4; ++k) {
    float4 f = *reinterpret_cast<const float4*>(s + k * 4);
    L[r][cg + k * 4 + 0] = f.x; L[r][cg + k * 4 + 1] = f.y;
    L[r][cg + k * 4 + 2] = f.z; L[r][cg + k * 4 + 3] = f.w;
  }
  __syncthreads();
  const int cr = tid >> 2;
  const int tg = (tid & 3) * 16;
  unsigned short* d = dst + (size_t)(cb * 64 + cr) * TT + tb * 64 + tg;
#pragma unroll
  for (int k = 0; k < 4; ++k) {
    ushort4 u;
    u.x = f2bf(L[tg + k * 4 + 0][cr]);
    u.y = f2bf(L[tg + k * 4 + 1][cr]);
    u.z = f2bf(L[tg + k * 4 + 2][cr]);
    u.w = f2bf(L[tg + k * 4 + 3][cr]);
    *reinterpret_cast<ushort4*>(d + k * 4) = u;
  }
}

// ---------------- flash attention: swapped-QK^T, in-register softmax ----------------
// Block = 4 waves = the 4 heads of one GQA kv-group, same 32-row q-tile.
// S^T = mfma32x32(K, Q^T): lane (qc,hi) holds S[q=qc][j=(r&3)+8*(r>>2)+4*hi].
// Softmax in-register; P repacked to PV A-frags via cvt_pk + permlane32_swap
// (dst = low-k word, src = high-k word); O rescale uses per-row alpha.
__global__ __launch_bounds__(256)
void attn_kernel(const unsigned short* __restrict__ qh,
                 const unsigned short* __restrict__ kh,
                 const unsigned short* __restrict__ vt,
                 unsigned short* __restrict__ y) {
  __shared__ __align__(16) unsigned short Ks[2][64 * 64];   // [j][d] swizzled
  __shared__ __align__(16) unsigned short Vts[2][64 * 64];  // [d][j] swizzled
  const int kvg = blockIdx.x;
  const int qt = (int)(gridDim.y - 1) - (int)blockIdx.y;  // heavy tiles first
  const int tid = threadIdx.x, wave = tid >> 6, lane = tid & 63;
  const int h = kvg * 4 + wave;
  const int qc = lane & 31, hi = lane >> 5;
  const int srow = lane >> 3;
  const int scol = (((lane & 7) ^ srow) << 3);

  // Q fragments: B-operand of 32x32x16 -> lane holds Q[qt*32+qc][ks*16+hi*8+e]
  bf16x8 qa[4];
  {
    const unsigned short* qrow = qh + ((size_t)h * TT + qt * 32 + qc) * HDIM + hi * 8;
#pragma unroll
    for (int ks = 0; ks < 4; ++ks)
      qa[ks] = *reinterpret_cast<const bf16x8*>(qrow + ks * 16);
  }

  f32x16 oA, oB;
#pragma unroll
  for (int r = 0; r < 16; ++r) { oA[r] = 0.f; oB[r] = 0.f; }
  float m_r = -1e30f, l_r = 0.f;

  const int njb = (qt >> 1) + 1;

#define A_STAGE(buf, jbx) do {                                                        \
    for (int i = 0; i < 2; ++i) {                                                     \
      int blk = wave * 2 + i;                                                         \
      int rr = blk * 8 + srow;                                                        \
      gl_lds16(kh + ((size_t)kvg * TT + (size_t)(jbx) * 64 + rr) * HDIM + scol,       \
               &Ks[buf][blk * 8 * 64]);                                               \
      gl_lds16(vt + ((size_t)(kvg * HDIM + rr)) * TT + (size_t)(jbx) * 64 + scol,     \
               &Vts[buf][blk * 8 * 64]);                                              \
    } } while (0)

  A_STAGE(0, 0);
  __syncthreads();
  int cur = 0;

  for (int jb = 0; jb < njb; ++jb) {
    if (jb + 1 < njb) A_STAGE(cur ^ 1, jb + 1);
    const bool last = (jb == njb - 1);
    const bool hasB = (!last) || (qt & 1);

    // S^T = K * Q^T  : A-frag = K row (lane&31), k = 16*ks + 8*hi + e
    f32x16 stA, stB;
#pragma unroll
    for (int r = 0; r < 16; ++r) { stA[r] = 0.f; stB[r] = 0.f; }
    __builtin_amdgcn_s_setprio(1);
#pragma unroll
    for (int ks = 0; ks < 4; ++ks) {
      int row = qc, g = 2 * ks + hi;
      bf16x8 kf = *reinterpret_cast<const bf16x8*>(&Ks[cur][row * 64 + ((g ^ (row & 7)) << 3)]);
      stA = __builtin_amdgcn_mfma_f32_32x32x16_bf16(kf, qa[ks], stA, 0, 0, 0);
    }
    if (hasB) {
#pragma unroll
      for (int ks = 0; ks < 4; ++ks) {
        int row = 32 + qc, g = 2 * ks + hi;
        bf16x8 kf = *reinterpret_cast<const bf16x8*>(&Ks[cur][row * 64 + ((g ^ (row & 7)) << 3)]);
        stB = __builtin_amdgcn_mfma_f32_32x32x16_bf16(kf, qa[ks], stB, 0, 0, 0);
      }
    }
    __builtin_amdgcn_s_setprio(0);

    if (last) {  // diagonal subtile mask: j_local > q_col
      if (qt & 1) {
#pragma unroll
        for (int r = 0; r < 16; ++r) {
          int jloc = (r & 3) + 8 * (r >> 2) + 4 * hi;
          stB[r] = (jloc > qc) ? -1e30f : stB[r];
        }
      } else {
#pragma unroll
        for (int r = 0; r < 16; ++r) {
          int jloc = (r & 3) + 8 * (r >> 2) + 4 * hi;
          stA[r] = (jloc > qc) ? -1e30f : stA[r];
        }
      }
    }

    // in-register online softmax (row = q = lane&31; halves combined via xor 32)
    float pm = stA[0];
#pragma unroll
    for (int r = 1; r < 16; ++r) pm = fmaxf(pm, stA[r]);
    if (hasB) {
#pragma unroll
      for (int r = 0; r < 16; ++r) pm = fmaxf(pm, stB[r]);
    }
    pm = fmaxf(pm, __shfl_xor(pm, 32));
    if (!__all(pm <= m_r + 8.f)) {  // defer-max (T13)
      float mn = fmaxf(m_r, pm);
      float al = __expf(m_r - mn);
      m_r = mn; l_r *= al;
      // O rows live in C/D space: alpha must be per O-row, not per-lane(qc)
#pragma unroll
      for (int r = 0; r < 16; ++r) {
        int qrow = (r & 3) + 8 * (r >> 2) + 4 * hi;
        float alr = __shfl(al, qrow);
        oA[r] *= alr; oB[r] *= alr;
      }
    }
    float sum = 0.f;
#pragma unroll
    for (int r = 0; r < 16; ++r) { stA[r] = __expf(stA[r] - m_r); sum += stA[r]; }
    if (hasB) {
#pragma unroll
      for (int r = 0; r < 16; ++r) { stB[r] = __expf(stB[r] - m_r); sum += stB[r]; }
    }
    sum += __shfl_xor(sum, 32);
    l_r += sum;

    // repack P -> bf16 A-frags (cvt_pk + permlane32_swap; dst = low-k word)
    W4 pf0, pf1, pf2, pf3;
#define REPACK(F0, F1, S)                                                   \
    F0.w[0] = pkbf(S[0], S[1]);  F0.w[1] = pkbf(S[2], S[3]);                \
    F0.w[2] = pkbf(S[4], S[5]);  F0.w[3] = pkbf(S[6], S[7]);                \
    swap32(F0.w[0], F0.w[2]);    swap32(F0.w[1], F0.w[3]);                  \
    F1.w[0] = pkbf(S[8], S[9]);  F1.w[1] = pkbf(S[10], S[11]);              \
    F1.w[2] = pkbf(S[12], S[13]); F1.w[3] = pkbf(S[14], S[15]);             \
    swap32(F1.w[0], F1.w[2]);    swap32(F1.w[1], F1.w[3]);
    REPACK(pf0, pf1, stA)
    if (hasB) { REPACK(pf2, pf3, stB) }
#undef REPACK

    // O += P V : B-frag = Vt row (d), k = 16*ks2 + 8*hi + e
    {
      const unsigned short* Vb = &Vts[cur][0];
      int r0 = qc, r1 = 32 + qc;
      int s0 = r0 & 7, s1 = r1 & 7;
      bf16x8 b;
      __builtin_amdgcn_s_setprio(1);
      b = *reinterpret_cast<const bf16x8*>(Vb + r0 * 64 + (((0 + hi) ^ s0) << 3));
      oA = __builtin_amdgcn_mfma_f32_32x32x16_bf16(pf0.v, b, oA, 0, 0, 0);
      b = *reinterpret_cast<const bf16x8*>(Vb + r1 * 64 + (((0 + hi) ^ s1) << 3));
      oB = __builtin_amdgcn_mfma_f32_32x32x16_bf16(pf0.v, b, oB, 0, 0, 0);
      b = *reinterpret_cast<const bf16x8*>(Vb + r0 * 64 + (((2 + hi) ^ s0) << 3));
      oA = __builtin_amdgcn_mfma_f32_32x32x16_bf16(pf1.v, b, oA, 0, 0, 0);
      b = *reinterpret_cast<const bf16x8*>(Vb + r1 * 64 + (((2 + hi) ^ s1) << 3));
      oB = __builtin_amdgcn_mfma_f32_32x32x16_bf16(pf1.v, b, oB, 0, 0, 0);
      if (hasB) {
        b = *reinterpret_cast<const bf16x8*>(Vb + r0 * 64 + (((4 + hi) ^ s0) << 3));
        oA = __builtin_amdgcn_mfma_f32_32x32x16_bf16(pf2.v, b, oA, 0, 0, 0);
        b = *reinterpret_cast<const bf16x8*>(Vb + r1 * 64 + (((4 + hi) ^ s1) << 3));
        oB = __builtin_amdgcn_mfma_f32_32x32x16_bf16(pf2.v, b, oB, 0, 0, 0);
        b = *reinterpret_cast<const bf16x8*>(Vb + r0 * 64 + (((6 + hi) ^ s0) << 3));
        oA = __builtin_amdgcn_mfma_f32_32x32x16_bf16(pf3.v, b, oA, 0, 0, 0);
        b = *reinterpret_cast<const bf16x8*>(Vb + r1 * 64 + (((6 + hi) ^ s1) << 3));
        oB = __builtin_amdgcn_mfma_f32_32x32x16_bf16(pf3.v, b, oB, 0, 0, 0);
      }
      __builtin_amdgcn_s_setprio(0);
    }
    __syncthreads();
    cur ^= 1;
  }
#undef A_STAGE

  // epilogue: O row q = (r&3)+8*(r>>2)+4*hi, col d = dsub*32 + qc
  float inv = 1.0f / l_r;
#pragma unroll
  for (int r = 0; r < 16; ++r) {
    int qrow = (r & 3) + 8 * (r >> 2) + 4 * hi;
    float iv = __shfl(inv, qrow);
    size_t base = (size_t)(qt * 32 + qrow) * DDIM + h * HDIM + qc;
    y[base] = f2bf(oA[r] * iv);
    y[base + 32] = f2bf(oB[r] * iv);
  }
}

// ---------------- launch ----------------
extern "C" void kernel_launch(void* const* d_in, const int* in_sizes, int n_in,
                              void* d_out, int out_size, void* d_ws, size_t ws_size,
                              hipStream_t stream) {
  const float* x  = (const float*)d_in[0];
  const float* wq = (const float*)d_in[1];
  const float* wk = (const float*)d_in[2];
  const float* wv = (const float*)d_in[3];
  const float* wo = (const float*)d_in[4];
  float* out = (float*)d_out;
  char* ws = (char*)d_ws;

  unsigned short* xb  = (unsigned short*)(ws + (size_t)0);
  unsigned short* wqb = (unsigned short*)(ws + ((size_t)8  << 20));
  unsigned short* wkb = (unsigned short*)(ws + ((size_t)16 << 20));
  unsigned short* wvb = (unsigned short*)(ws + ((size_t)18 << 20));
  unsigned short* wob = (unsigned short*)(ws + ((size_t)20 << 20));
  float*          qf  = (float*)(ws + ((size_t)28 << 20));
  float*          kf  = (float*)(ws + ((size_t)44 << 20));
  float*          vf  = (float*)(ws + ((size_t)48 << 20));
  unsigned short* qhb = (unsigned short*)(ws + ((size_t)52 << 20));
  unsigned short* khb = (unsigned short*)(ws + ((size_t)60 << 20));
  unsigned short* vtb = (unsigned short*)(ws + ((size_t)62 << 20));
  unsigned short* yb  = (unsigned short*)(ws + ((size_t)64 << 20));

  cast5_kernel<<<14336, 256, 0, stream>>>(x, wq, wk, wv, wo, xb, wqb, wkb, wvb, wob);

  qkv_gemm_kernel<<<dim3(16, 24), 256, 0, stream>>>(xb, wqb, wkb, wvb, qf, kf, vf);

  rope_transpose_kernel<<<8192, 256, 0, stream>>>(qf, qhb, 10, 0.125f);
  rope_transpose_kernel<<<2048, 256, 0, stream>>>(kf, khb, 8, 1.0f);
  transpose_v_kernel<<<256, 256, 0, stream>>>(vf, vtb);

  attn_kernel<<<dim3(8, 64), 256, 0, stream>>>(qhb, khb, vtb, yb);

  gemm_bt_kernel<<<dim3(16, 16), 256, 0, stream>>>(yb, wob, out, 2048, 2048);
}